// Round 1
// baseline (504.392 us; speedup 1.0000x reference)
//
#include <hip/hip_runtime.h>
#include <hip/hip_bf16.h>

#define TOKENS 512
#define IN_F 8192
#define OUT_F 8192
#define RANK 64
#define NNZ 8192

typedef __attribute__((ext_vector_type(8))) short short8;
typedef __attribute__((ext_vector_type(4))) float f32x4;
typedef __attribute__((ext_vector_type(4))) int int4v;

__device__ __forceinline__ unsigned short f2bf(float f) {
  unsigned int u = __builtin_bit_cast(unsigned int, f);
  u += 0x7FFFu + ((u >> 16) & 1u);
  return (unsigned short)(u >> 16);
}
__device__ __forceinline__ float bf2f(unsigned short b) {
  unsigned int u = ((unsigned int)b) << 16;
  return __builtin_bit_cast(float, u);
}

__device__ __forceinline__ void gload_lds16(const void* g, void* l) {
  __builtin_amdgcn_global_load_lds(
      (const __attribute__((address_space(1))) unsigned int*)(g),
      (__attribute__((address_space(3))) unsigned int*)(l), 16, 0, 0);
}

// K1: quantize x -> x_q (integer values) stored as bf16
__global__ __launch_bounds__(256) void k_quant(const float* __restrict__ x,
                                               const float* __restrict__ smooth,
                                               const float* __restrict__ act,
                                               unsigned short* __restrict__ Abf) {
  int idx = blockIdx.x * 256 + threadIdx.x;
  int base = idx * 4;
  int col = base & (IN_F - 1);
  float a = act[0];
  float4 xx = *(const float4*)(x + base);
  float4 ss = *(const float4*)(smooth + col);
  float q0 = fminf(fmaxf(rintf((xx.x / ss.x) / a), -128.f), 127.f);
  float q1 = fminf(fmaxf(rintf((xx.y / ss.y) / a), -128.f), 127.f);
  float q2 = fminf(fmaxf(rintf((xx.z / ss.z) / a), -128.f), 127.f);
  float q3 = fminf(fmaxf(rintf((xx.w / ss.w) / a), -128.f), 127.f);
  ushort4 o;
  o.x = f2bf(q0); o.y = f2bf(q1); o.z = f2bf(q2); o.w = f2bf(q3);
  *(ushort4*)(Abf + base) = o;
}

// K2: t[512][64] = (x_dq @ V) * S   (a and S folded in; atomic K-split accum)
__global__ __launch_bounds__(256) void k_lr1(const unsigned short* __restrict__ Abf,
                                             const float* __restrict__ V,
                                             const float* __restrict__ S,
                                             const float* __restrict__ act,
                                             float* __restrict__ t) {
  int bid = blockIdx.x;
  int mb = (bid & 3) * 128;
  int kb0 = (bid >> 2) * 512;
  int tid = threadIdx.x, w = tid >> 6, l = tid & 63;
  int lr = l & 15, lg = l >> 4;
  f32x4 acc[2][4] = {};
  for (int ks = 0; ks < 16; ++ks) {
    int kb = kb0 + ks * 32;
    short8 af[2];
#pragma unroll
    for (int fi = 0; fi < 2; ++fi) {
      int row = mb + w * 32 + fi * 16 + lr;
      af[fi] = *(const short8*)(Abf + (size_t)row * IN_F + kb + lg * 8);
    }
    short8 bfr[4];
#pragma unroll
    for (int fj = 0; fj < 4; ++fj) {
      int rk = fj * 16 + lr;
      short8 bv;
#pragma unroll
      for (int j = 0; j < 8; ++j)
        bv[j] = (short)f2bf(V[(size_t)(kb + lg * 8 + j) * RANK + rk]);
      bfr[fj] = bv;
    }
#pragma unroll
    for (int fi = 0; fi < 2; ++fi)
#pragma unroll
      for (int fj = 0; fj < 4; ++fj)
        acc[fi][fj] = __builtin_amdgcn_mfma_f32_16x16x32_bf16(af[fi], bfr[fj], acc[fi][fj], 0, 0, 0);
  }
  float a = act[0];
#pragma unroll
  for (int fi = 0; fi < 2; ++fi)
#pragma unroll
    for (int fj = 0; fj < 4; ++fj) {
      int rk = fj * 16 + lr;
      float sc = a * S[rk];
#pragma unroll
      for (int r = 0; r < 4; ++r) {
        int tok = mb + w * 32 + fi * 16 + lg * 4 + r;
        atomicAdd(t + tok * RANK + rk, acc[fi][fj][r] * sc);
      }
    }
}

// K3: out = bias + t @ U^T   (first writer of out)
__global__ __launch_bounds__(256) void k_lr2(const float* __restrict__ t,
                                             const float* __restrict__ U,
                                             const float* __restrict__ bias,
                                             float* __restrict__ out) {
  int bid = blockIdx.x;
  int mb = (bid & 3) * 128;
  int nb = (bid >> 2) * 128;
  int tid = threadIdx.x, w = tid >> 6, l = tid & 63;
  int lr = l & 15, lg = l >> 4;
  int wm = w >> 1, wn = w & 1;
  f32x4 acc[4][4] = {};
#pragma unroll
  for (int kk = 0; kk < 2; ++kk) {
    short8 af[4], bfr[4];
#pragma unroll
    for (int fi = 0; fi < 4; ++fi) {
      int row = mb + wm * 64 + fi * 16 + lr;
      const float4* tp = (const float4*)(t + (size_t)row * RANK + kk * 32 + lg * 8);
      float4 t0 = tp[0], t1 = tp[1];
      af[fi][0] = f2bf(t0.x); af[fi][1] = f2bf(t0.y);
      af[fi][2] = f2bf(t0.z); af[fi][3] = f2bf(t0.w);
      af[fi][4] = f2bf(t1.x); af[fi][5] = f2bf(t1.y);
      af[fi][6] = f2bf(t1.z); af[fi][7] = f2bf(t1.w);
    }
#pragma unroll
    for (int fj = 0; fj < 4; ++fj) {
      int row = nb + wn * 64 + fj * 16 + lr;
      const float4* up = (const float4*)(U + (size_t)row * RANK + kk * 32 + lg * 8);
      float4 u0 = up[0], u1 = up[1];
      bfr[fj][0] = f2bf(u0.x); bfr[fj][1] = f2bf(u0.y);
      bfr[fj][2] = f2bf(u0.z); bfr[fj][3] = f2bf(u0.w);
      bfr[fj][4] = f2bf(u1.x); bfr[fj][5] = f2bf(u1.y);
      bfr[fj][6] = f2bf(u1.z); bfr[fj][7] = f2bf(u1.w);
    }
#pragma unroll
    for (int fi = 0; fi < 4; ++fi)
#pragma unroll
      for (int fj = 0; fj < 4; ++fj)
        acc[fi][fj] = __builtin_amdgcn_mfma_f32_16x16x32_bf16(af[fi], bfr[fj], acc[fi][fj], 0, 0, 0);
  }
#pragma unroll
  for (int fj = 0; fj < 4; ++fj) {
    int o = nb + wn * 64 + fj * 16 + lr;
    float b = bias[o];
#pragma unroll
    for (int fi = 0; fi < 4; ++fi)
#pragma unroll
      for (int r = 0; r < 4; ++r) {
        int tok = mb + wm * 64 + fi * 16 + lg * 4 + r;
        out[(size_t)tok * OUT_F + o] = b + acc[fi][fj][r];
      }
  }
}

// K4: outliers — one block per token; row of x_q is L1-resident
__global__ __launch_bounds__(256) void k_outlier(const unsigned short* __restrict__ Abf,
                                                 const int* __restrict__ rows,
                                                 const int* __restrict__ cols,
                                                 const float* __restrict__ vals,
                                                 const float* __restrict__ act,
                                                 float* __restrict__ out) {
  int tk = blockIdx.x;
  float a = act[0];
  for (int i = threadIdx.x; i < NNZ; i += 256) {
    int r = rows[i], c = cols[i];
    float v = vals[i];
    float xq = bf2f(Abf[(size_t)tk * IN_F + c]);
    atomicAdd(out + (size_t)tk * OUT_F + r, a * xq * v);
  }
}

// K5: out += x_q @ Wq^T * (a * wscale[o]); 256x64 tile, BK=32, 8 waves
__global__ __launch_bounds__(512) void k_gemm(const unsigned short* __restrict__ Abf,
                                              const int* __restrict__ W,
                                              const float* __restrict__ wscale,
                                              const float* __restrict__ act,
                                              float* __restrict__ out) {
  __shared__ __align__(16) unsigned short As[256 * 32];
  __shared__ __align__(16) unsigned short Bs[64 * 32];
  int bid = blockIdx.x;
  int mb = (bid & 1) * 256;
  int nb = (bid >> 1) * 64;
  int tid = threadIdx.x, w = tid >> 6, l = tid & 63;
  int lr = l & 15, lg = l >> 4;
  int wm = w >> 1, wn = w & 1;
  f32x4 acc[4][2] = {};
  for (int kt = 0; kt < 256; ++kt) {
    int kb = kt * 32;
    // stage A (bf16) via global_load_lds, 2 x 16B per thread
#pragma unroll
    for (int i = 0; i < 2; ++i) {
      int off = (i * 512 + tid) * 8;
      int row = off >> 5, col = off & 31;
      gload_lds16(Abf + (size_t)(mb + row) * IN_F + kb + col,
                  As + (size_t)(i * 512 + w * 64) * 8);
    }
    // stage B: int32 -> bf16, 1 x int4 per thread
    {
      int off = tid * 4;
      int row = off >> 5, col = off & 31;
      int4v bv = *(const int4v*)(W + (size_t)(nb + row) * IN_F + kb + col);
      ushort4 p;
      p.x = f2bf((float)bv.x); p.y = f2bf((float)bv.y);
      p.z = f2bf((float)bv.z); p.w = f2bf((float)bv.w);
      *(ushort4*)(Bs + off) = p;
    }
    __syncthreads();
    short8 af[4], bfr[2];
#pragma unroll
    for (int fi = 0; fi < 4; ++fi)
      af[fi] = *(const short8*)(As + (size_t)(wm * 64 + fi * 16 + lr) * 32 + lg * 8);
#pragma unroll
    for (int fj = 0; fj < 2; ++fj)
      bfr[fj] = *(const short8*)(Bs + (size_t)(wn * 32 + fj * 16 + lr) * 32 + lg * 8);
#pragma unroll
    for (int fi = 0; fi < 4; ++fi)
#pragma unroll
      for (int fj = 0; fj < 2; ++fj)
        acc[fi][fj] = __builtin_amdgcn_mfma_f32_16x16x32_bf16(af[fi], bfr[fj], acc[fi][fj], 0, 0, 0);
    __syncthreads();
  }
  float a = act[0];
#pragma unroll
  for (int fj = 0; fj < 2; ++fj) {
    int o = nb + wn * 32 + fj * 16 + lr;
    float sc = a * wscale[o];
#pragma unroll
    for (int fi = 0; fi < 4; ++fi)
#pragma unroll
      for (int r = 0; r < 4; ++r) {
        int tok = mb + wm * 64 + fi * 16 + lg * 4 + r;
        out[(size_t)tok * OUT_F + o] += acc[fi][fj][r] * sc;
      }
  }
}

extern "C" void kernel_launch(void* const* d_in, const int* in_sizes, int n_in,
                              void* d_out, int out_size, void* d_ws, size_t ws_size,
                              hipStream_t stream) {
  const float* x = (const float*)d_in[0];
  const int* W = (const int*)d_in[1];
  const float* wscale = (const float*)d_in[2];
  const float* smooth = (const float*)d_in[3];
  const float* act = (const float*)d_in[4];
  const int* orow = (const int*)d_in[5];
  const int* ocol = (const int*)d_in[6];
  const float* oval = (const float*)d_in[7];
  const float* U = (const float*)d_in[8];
  const float* S = (const float*)d_in[9];
  const float* V = (const float*)d_in[10];
  const float* bias = (const float*)d_in[11];
  float* out = (float*)d_out;

  unsigned short* Abf = (unsigned short*)d_ws;
  float* t = (float*)((char*)d_ws + (size_t)TOKENS * IN_F * 2);

  hipMemsetAsync(t, 0, TOKENS * RANK * sizeof(float), stream);
  k_quant<<<(TOKENS * IN_F / 4) / 256, 256, 0, stream>>>(x, smooth, act, Abf);
  k_lr1<<<64, 256, 0, stream>>>(Abf, V, S, act, t);
  k_lr2<<<256, 256, 0, stream>>>(t, U, bias, out);
  k_outlier<<<TOKENS, 256, 0, stream>>>(Abf, orow, ocol, oval, act, out);
  k_gemm<<<256, 512, 0, stream>>>(Abf, W, wscale, act, out);
}

// Round 2
// 221.981 us; speedup vs baseline: 2.2722x; 2.2722x over previous
//
#include <hip/hip_runtime.h>
#include <hip/hip_bf16.h>

#define TOKENS 512
#define IN_F 8192
#define OUT_F 8192
#define RANK 64
#define NNZ 8192

typedef __attribute__((ext_vector_type(8))) short short8;
typedef __attribute__((ext_vector_type(8))) unsigned short ushort8;
typedef __attribute__((ext_vector_type(4))) float f32x4;
typedef __attribute__((ext_vector_type(4))) int int4v;

__device__ __forceinline__ unsigned short f2bf(float f) {
  unsigned int u = __builtin_bit_cast(unsigned int, f);
  u += 0x7FFFu + ((u >> 16) & 1u);
  return (unsigned short)(u >> 16);
}
__device__ __forceinline__ float bf2f(unsigned short b) {
  unsigned int u = ((unsigned int)b) << 16;
  return __builtin_bit_cast(float, u);
}

__device__ __forceinline__ void gload_lds16(const void* g, void* l) {
  __builtin_amdgcn_global_load_lds(
      (const __attribute__((address_space(1))) unsigned int*)(g),
      (__attribute__((address_space(3))) unsigned int*)(l), 16, 0, 0);
}

// K1: quantize x -> x_q (integer values) stored as bf16 (exact in bf16)
__global__ __launch_bounds__(256) void k_quant(const float* __restrict__ x,
                                               const float* __restrict__ smooth,
                                               const float* __restrict__ act,
                                               unsigned short* __restrict__ Abf) {
  int idx = blockIdx.x * 256 + threadIdx.x;
  int base = idx * 4;
  int col = base & (IN_F - 1);
  float a = act[0];
  float4 xx = *(const float4*)(x + base);
  float4 ss = *(const float4*)(smooth + col);
  float q0 = fminf(fmaxf(rintf((xx.x / ss.x) / a), -128.f), 127.f);
  float q1 = fminf(fmaxf(rintf((xx.y / ss.y) / a), -128.f), 127.f);
  float q2 = fminf(fmaxf(rintf((xx.z / ss.z) / a), -128.f), 127.f);
  float q3 = fminf(fmaxf(rintf((xx.w / ss.w) / a), -128.f), 127.f);
  ushort4 o;
  o.x = f2bf(q0); o.y = f2bf(q1); o.z = f2bf(q2); o.w = f2bf(q3);
  *(ushort4*)(Abf + base) = o;
}

// K2: t[512][64] = (x_dq @ V) * S   (a and S folded in; atomic K-split accum)
__global__ __launch_bounds__(256) void k_lr1(const unsigned short* __restrict__ Abf,
                                             const float* __restrict__ V,
                                             const float* __restrict__ S,
                                             const float* __restrict__ act,
                                             float* __restrict__ t) {
  int bid = blockIdx.x;
  int mb = (bid & 3) * 128;
  int kb0 = (bid >> 2) * 512;
  int tid = threadIdx.x, w = tid >> 6, l = tid & 63;
  int lr = l & 15, lg = l >> 4;
  f32x4 acc[2][4] = {};
  for (int ks = 0; ks < 16; ++ks) {
    int kb = kb0 + ks * 32;
    short8 af[2];
#pragma unroll
    for (int fi = 0; fi < 2; ++fi) {
      int row = mb + w * 32 + fi * 16 + lr;
      af[fi] = *(const short8*)(Abf + (size_t)row * IN_F + kb + lg * 8);
    }
    short8 bfr[4];
#pragma unroll
    for (int fj = 0; fj < 4; ++fj) {
      int rk = fj * 16 + lr;
      short8 bv;
#pragma unroll
      for (int j = 0; j < 8; ++j)
        bv[j] = (short)f2bf(V[(size_t)(kb + lg * 8 + j) * RANK + rk]);
      bfr[fj] = bv;
    }
#pragma unroll
    for (int fi = 0; fi < 2; ++fi)
#pragma unroll
      for (int fj = 0; fj < 4; ++fj)
        acc[fi][fj] = __builtin_amdgcn_mfma_f32_16x16x32_bf16(af[fi], bfr[fj], acc[fi][fj], 0, 0, 0);
  }
  float a = act[0];
#pragma unroll
  for (int fi = 0; fi < 2; ++fi)
#pragma unroll
    for (int fj = 0; fj < 4; ++fj) {
      int rk = fj * 16 + lr;
      float sc = a * S[rk];
#pragma unroll
      for (int r = 0; r < 4; ++r) {
        int tok = mb + w * 32 + fi * 16 + lg * 4 + r;
        atomicAdd(t + tok * RANK + rk, acc[fi][fj][r] * sc);
      }
    }
}

// K3: out = bias + t @ U^T   (first writer of out)
__global__ __launch_bounds__(256) void k_lr2(const float* __restrict__ t,
                                             const float* __restrict__ U,
                                             const float* __restrict__ bias,
                                             float* __restrict__ out) {
  int bid = blockIdx.x;
  int mb = (bid & 3) * 128;
  int nb = (bid >> 2) * 128;
  int tid = threadIdx.x, w = tid >> 6, l = tid & 63;
  int lr = l & 15, lg = l >> 4;
  int wm = w >> 1, wn = w & 1;
  f32x4 acc[4][4] = {};
#pragma unroll
  for (int kk = 0; kk < 2; ++kk) {
    short8 af[4], bfr[4];
#pragma unroll
    for (int fi = 0; fi < 4; ++fi) {
      int row = mb + wm * 64 + fi * 16 + lr;
      const float4* tp = (const float4*)(t + (size_t)row * RANK + kk * 32 + lg * 8);
      float4 t0 = tp[0], t1 = tp[1];
      af[fi][0] = f2bf(t0.x); af[fi][1] = f2bf(t0.y);
      af[fi][2] = f2bf(t0.z); af[fi][3] = f2bf(t0.w);
      af[fi][4] = f2bf(t1.x); af[fi][5] = f2bf(t1.y);
      af[fi][6] = f2bf(t1.z); af[fi][7] = f2bf(t1.w);
    }
#pragma unroll
    for (int fj = 0; fj < 4; ++fj) {
      int row = nb + wn * 64 + fj * 16 + lr;
      const float4* up = (const float4*)(U + (size_t)row * RANK + kk * 32 + lg * 8);
      float4 u0 = up[0], u1 = up[1];
      bfr[fj][0] = f2bf(u0.x); bfr[fj][1] = f2bf(u0.y);
      bfr[fj][2] = f2bf(u0.z); bfr[fj][3] = f2bf(u0.w);
      bfr[fj][4] = f2bf(u1.x); bfr[fj][5] = f2bf(u1.y);
      bfr[fj][6] = f2bf(u1.z); bfr[fj][7] = f2bf(u1.w);
    }
#pragma unroll
    for (int fi = 0; fi < 4; ++fi)
#pragma unroll
      for (int fj = 0; fj < 4; ++fj)
        acc[fi][fj] = __builtin_amdgcn_mfma_f32_16x16x32_bf16(af[fi], bfr[fj], acc[fi][fj], 0, 0, 0);
  }
#pragma unroll
  for (int fj = 0; fj < 4; ++fj) {
    int o = nb + wn * 64 + fj * 16 + lr;
    float b = bias[o];
#pragma unroll
    for (int fi = 0; fi < 4; ++fi)
#pragma unroll
      for (int r = 0; r < 4; ++r) {
        int tok = mb + wm * 64 + fi * 16 + lg * 4 + r;
        out[(size_t)tok * OUT_F + o] = b + acc[fi][fj][r];
      }
  }
}

// K4: outliers — one block per token; accumulate in a 32KB LDS row, then one
// coalesced RMW pass over out[t][:]. Runs before k_gemm in stream order.
__global__ __launch_bounds__(256) void k_outlier(const unsigned short* __restrict__ Abf,
                                                 const int* __restrict__ rows,
                                                 const int* __restrict__ cols,
                                                 const float* __restrict__ vals,
                                                 const float* __restrict__ act,
                                                 float* __restrict__ out) {
  __shared__ float accr[OUT_F];
  int tk = blockIdx.x;
  for (int i = threadIdx.x; i < OUT_F; i += 256) accr[i] = 0.f;
  __syncthreads();
  float a = act[0];
  for (int i = threadIdx.x; i < NNZ; i += 256) {
    int r = rows[i], c = cols[i];
    float v = vals[i];
    float xq = bf2f(Abf[(size_t)tk * IN_F + c]);
    atomicAdd(accr + r, a * xq * v);
  }
  __syncthreads();
  float* orow = out + (size_t)tk * OUT_F;
  for (int i = threadIdx.x; i < OUT_F; i += 256) orow[i] += accr[i];
}

// K5: out += x_q @ Wq^T * (a*wscale[o]); 128x128 tile, BK=64, 8 waves,
// double-buffered LDS (1 barrier/iter), KSPLIT=2, XOR-swizzled LDS,
// XCD-chunked block swizzle, atomicAdd epilogue.
__global__ __launch_bounds__(512, 4) void k_gemm(const unsigned short* __restrict__ Abf,
                                                 const int* __restrict__ W,
                                                 const float* __restrict__ wscale,
                                                 const float* __restrict__ act,
                                                 float* __restrict__ out) {
  __shared__ __align__(16) unsigned short As[2][128 * 64];
  __shared__ __align__(16) unsigned short Bs[2][128 * 64];

  // decode: d = (g%8) + 8*(mb + 4*(g/8)), g = nb + 64*ks
  int d = blockIdx.x;
  int xcd = d & 7, q = d >> 3;
  int mb = q & 3, ghi = q >> 2;
  int g = xcd + 8 * ghi;
  int nb = g & 63, ks = g >> 6;
  int kb0 = ks * 4096;

  int tid = threadIdx.x, w = tid >> 6, l = tid & 63;
  int lr = l & 15, lg = l >> 4;
  int wm = w >> 1, wn = w & 1;  // 4M x 2N waves; wave tile 32x64

  f32x4 acc[2][4] = {};
  int4v wreg[4];

  const int rB = tid >> 2;           // W staging row (0..127)
  const int k0 = (tid & 3) * 16;     // W staging k offset (elements)

  // W (int32) -> registers
  auto LOAD_W = [&](int kb) {
    const int* wp = W + (size_t)(nb * 128 + rB) * IN_F + kb + k0;
#pragma unroll
    for (int j = 0; j < 4; ++j) wreg[j] = ((const int4v*)wp)[j];
  };
  // A (bf16) -> LDS direct, source pre-swizzled so swizzled-read matches
  auto STAGE_A = [&](unsigned short* Abuf, int kb) {
#pragma unroll
    for (int i = 0; i < 2; ++i) {
      int lidx = i * 512 + w * 64;  // wave-uniform 16B-unit base
      int ell = lidx + l;
      int r = ell >> 3, up = ell & 7;
      int u = up ^ (r & 7);
      gload_lds16(Abf + (size_t)(mb * 128 + r) * IN_F + kb + u * 8,
                  Abuf + (size_t)lidx * 8);
    }
  };
  // convert wreg -> bf16, write swizzled
  auto WRITE_B = [&](unsigned short* Bbuf) {
    ushort8 p0, p1;
#pragma unroll
    for (int j = 0; j < 8; ++j) p0[j] = f2bf((float)wreg[j >> 2][j & 3]);
#pragma unroll
    for (int j = 0; j < 8; ++j) p1[j] = f2bf((float)wreg[2 + (j >> 2)][j & 3]);
    int u0 = (tid & 3) * 2;
    *(ushort8*)(Bbuf + ((size_t)rB * 8 + (u0 ^ (rB & 7))) * 8) = p0;
    *(ushort8*)(Bbuf + ((size_t)rB * 8 + ((u0 + 1) ^ (rB & 7))) * 8) = p1;
  };
  auto LDF = [&](const unsigned short* buf, int row, int uq) -> short8 {
    return *(const short8*)(buf + ((size_t)row * 8 + (uq ^ (row & 7))) * 8);
  };

  // prologue
  LOAD_W(kb0);
  STAGE_A(As[0], kb0);
  WRITE_B(Bs[0]);
  __syncthreads();

  const int NT = 64;  // 4096 / 64
  for (int kt = 0; kt < NT; ++kt) {
    const int cur = kt & 1;
    const unsigned short* Ac = As[cur];
    const unsigned short* Bc = Bs[cur];
    if (kt + 1 < NT) {
      LOAD_W(kb0 + (kt + 1) * 64);
      STAGE_A(As[cur ^ 1], kb0 + (kt + 1) * 64);
    }
#pragma unroll
    for (int ksub = 0; ksub < 2; ++ksub) {
      int uq = ksub * 4 + lg;
      short8 af0 = LDF(Ac, wm * 32 + lr, uq);
      short8 af1 = LDF(Ac, wm * 32 + 16 + lr, uq);
      short8 b0 = LDF(Bc, wn * 64 + lr, uq);
      short8 b1 = LDF(Bc, wn * 64 + 16 + lr, uq);
      short8 b2 = LDF(Bc, wn * 64 + 32 + lr, uq);
      short8 b3 = LDF(Bc, wn * 64 + 48 + lr, uq);
      acc[0][0] = __builtin_amdgcn_mfma_f32_16x16x32_bf16(af0, b0, acc[0][0], 0, 0, 0);
      acc[0][1] = __builtin_amdgcn_mfma_f32_16x16x32_bf16(af0, b1, acc[0][1], 0, 0, 0);
      acc[0][2] = __builtin_amdgcn_mfma_f32_16x16x32_bf16(af0, b2, acc[0][2], 0, 0, 0);
      acc[0][3] = __builtin_amdgcn_mfma_f32_16x16x32_bf16(af0, b3, acc[0][3], 0, 0, 0);
      acc[1][0] = __builtin_amdgcn_mfma_f32_16x16x32_bf16(af1, b0, acc[1][0], 0, 0, 0);
      acc[1][1] = __builtin_amdgcn_mfma_f32_16x16x32_bf16(af1, b1, acc[1][1], 0, 0, 0);
      acc[1][2] = __builtin_amdgcn_mfma_f32_16x16x32_bf16(af1, b2, acc[1][2], 0, 0, 0);
      acc[1][3] = __builtin_amdgcn_mfma_f32_16x16x32_bf16(af1, b3, acc[1][3], 0, 0, 0);
    }
    if (kt + 1 < NT) WRITE_B(Bs[cur ^ 1]);
    __syncthreads();
  }

  float a = act[0];
#pragma unroll
  for (int fj = 0; fj < 4; ++fj) {
    int o = nb * 128 + wn * 64 + fj * 16 + lr;
    float sc = a * wscale[o];
#pragma unroll
    for (int fi = 0; fi < 2; ++fi)
#pragma unroll
      for (int rr = 0; rr < 4; ++rr) {
        int tok = mb * 128 + wm * 32 + fi * 16 + lg * 4 + rr;
        atomicAdd(out + (size_t)tok * OUT_F + o, acc[fi][fj][rr] * sc);
      }
  }
}

extern "C" void kernel_launch(void* const* d_in, const int* in_sizes, int n_in,
                              void* d_out, int out_size, void* d_ws, size_t ws_size,
                              hipStream_t stream) {
  const float* x = (const float*)d_in[0];
  const int* W = (const int*)d_in[1];
  const float* wscale = (const float*)d_in[2];
  const float* smooth = (const float*)d_in[3];
  const float* act = (const float*)d_in[4];
  const int* orow = (const int*)d_in[5];
  const int* ocol = (const int*)d_in[6];
  const float* oval = (const float*)d_in[7];
  const float* U = (const float*)d_in[8];
  const float* S = (const float*)d_in[9];
  const float* V = (const float*)d_in[10];
  const float* bias = (const float*)d_in[11];
  float* out = (float*)d_out;

  unsigned short* Abf = (unsigned short*)d_ws;
  float* t = (float*)((char*)d_ws + (size_t)TOKENS * IN_F * 2);

  hipMemsetAsync(t, 0, TOKENS * RANK * sizeof(float), stream);
  k_quant<<<(TOKENS * IN_F / 4) / 256, 256, 0, stream>>>(x, smooth, act, Abf);
  k_lr1<<<64, 256, 0, stream>>>(Abf, V, S, act, t);
  k_lr2<<<256, 256, 0, stream>>>(t, U, bias, out);
  k_outlier<<<TOKENS, 256, 0, stream>>>(Abf, orow, ocol, oval, act, out);
  k_gemm<<<512, 512, 0, stream>>>(Abf, W, wscale, act, out);
}

// Round 3
// 187.597 us; speedup vs baseline: 2.6887x; 1.1833x over previous
//
#include <hip/hip_runtime.h>
#include <hip/hip_bf16.h>

#define TOKENS 512
#define IN_F 8192
#define OUT_F 8192
#define RANK 64
#define NNZ 8192

#define KSPLIT 4
#define KRANGE (IN_F / KSPLIT)   // 2048
#define BN 64
#define BK 64
#define NT (KRANGE / BK)         // 32

typedef __attribute__((ext_vector_type(8))) short short8;
typedef __attribute__((ext_vector_type(4))) float f32x4;
typedef __attribute__((ext_vector_type(4))) int int4v;

__device__ __forceinline__ unsigned short f2bf(float f) {
  unsigned int u = __builtin_bit_cast(unsigned int, f);
  u += 0x7FFFu + ((u >> 16) & 1u);
  return (unsigned short)(u >> 16);
}
__device__ __forceinline__ float bf2f(unsigned short b) {
  unsigned int u = ((unsigned int)b) << 16;
  return __builtin_bit_cast(float, u);
}

__device__ __forceinline__ void gload_lds16(const void* g, void* l) {
  __builtin_amdgcn_global_load_lds(
      (const __attribute__((address_space(1))) unsigned int*)(g),
      (__attribute__((address_space(3))) unsigned int*)(l), 16, 0, 0);
}

// K1: quantize x -> x_q; write bf16 copy (lr1/outlier) and i8 copy (gemm)
__global__ __launch_bounds__(256) void k_quant(const float* __restrict__ x,
                                               const float* __restrict__ smooth,
                                               const float* __restrict__ act,
                                               unsigned short* __restrict__ Abf,
                                               unsigned char* __restrict__ Aq) {
  int idx = blockIdx.x * 256 + threadIdx.x;
  int base = idx * 4;
  int col = base & (IN_F - 1);
  float a = act[0];
  float4 xx = *(const float4*)(x + base);
  float4 ss = *(const float4*)(smooth + col);
  float q0 = fminf(fmaxf(rintf((xx.x / ss.x) / a), -128.f), 127.f);
  float q1 = fminf(fmaxf(rintf((xx.y / ss.y) / a), -128.f), 127.f);
  float q2 = fminf(fmaxf(rintf((xx.z / ss.z) / a), -128.f), 127.f);
  float q3 = fminf(fmaxf(rintf((xx.w / ss.w) / a), -128.f), 127.f);
  ushort4 o;
  o.x = f2bf(q0); o.y = f2bf(q1); o.z = f2bf(q2); o.w = f2bf(q3);
  *(ushort4*)(Abf + base) = o;
  int i0 = (int)q0, i1 = (int)q1, i2 = (int)q2, i3 = (int)q3;
  unsigned int p = (i0 & 0xFF) | ((i1 & 0xFF) << 8) | ((i2 & 0xFF) << 16) |
                   ((unsigned)(i3 & 0xFF) << 24);
  *(unsigned int*)(Aq + base) = p;
}

// K2: t[512][64] = (x_dq @ V) * S   (a and S folded in; atomic K-split accum)
__global__ __launch_bounds__(256) void k_lr1(const unsigned short* __restrict__ Abf,
                                             const float* __restrict__ V,
                                             const float* __restrict__ S,
                                             const float* __restrict__ act,
                                             float* __restrict__ t) {
  int bid = blockIdx.x;
  int mb = (bid & 3) * 128;
  int kb0 = (bid >> 2) * 512;
  int tid = threadIdx.x, w = tid >> 6, l = tid & 63;
  int lr = l & 15, lg = l >> 4;
  f32x4 acc[2][4] = {};
  for (int ks = 0; ks < 16; ++ks) {
    int kb = kb0 + ks * 32;
    short8 af[2];
#pragma unroll
    for (int fi = 0; fi < 2; ++fi) {
      int row = mb + w * 32 + fi * 16 + lr;
      af[fi] = *(const short8*)(Abf + (size_t)row * IN_F + kb + lg * 8);
    }
    short8 bfr[4];
#pragma unroll
    for (int fj = 0; fj < 4; ++fj) {
      int rk = fj * 16 + lr;
      short8 bv;
#pragma unroll
      for (int j = 0; j < 8; ++j)
        bv[j] = (short)f2bf(V[(size_t)(kb + lg * 8 + j) * RANK + rk]);
      bfr[fj] = bv;
    }
#pragma unroll
    for (int fi = 0; fi < 2; ++fi)
#pragma unroll
      for (int fj = 0; fj < 4; ++fj)
        acc[fi][fj] = __builtin_amdgcn_mfma_f32_16x16x32_bf16(af[fi], bfr[fj], acc[fi][fj], 0, 0, 0);
  }
  float a = act[0];
#pragma unroll
  for (int fi = 0; fi < 2; ++fi)
#pragma unroll
    for (int fj = 0; fj < 4; ++fj) {
      int rk = fj * 16 + lr;
      float sc = a * S[rk];
#pragma unroll
      for (int r = 0; r < 4; ++r) {
        int tok = mb + w * 32 + fi * 16 + lg * 4 + r;
        atomicAdd(t + tok * RANK + rk, acc[fi][fj][r] * sc);
      }
    }
}

// K3: out = bias + t @ U^T   (first writer of out)
__global__ __launch_bounds__(256) void k_lr2(const float* __restrict__ t,
                                             const float* __restrict__ U,
                                             const float* __restrict__ bias,
                                             float* __restrict__ out) {
  int bid = blockIdx.x;
  int mb = (bid & 3) * 128;
  int nb = (bid >> 2) * 128;
  int tid = threadIdx.x, w = tid >> 6, l = tid & 63;
  int lr = l & 15, lg = l >> 4;
  int wm = w >> 1, wn = w & 1;
  f32x4 acc[4][4] = {};
#pragma unroll
  for (int kk = 0; kk < 2; ++kk) {
    short8 af[4], bfr[4];
#pragma unroll
    for (int fi = 0; fi < 4; ++fi) {
      int row = mb + wm * 64 + fi * 16 + lr;
      const float4* tp = (const float4*)(t + (size_t)row * RANK + kk * 32 + lg * 8);
      float4 t0 = tp[0], t1 = tp[1];
      af[fi][0] = f2bf(t0.x); af[fi][1] = f2bf(t0.y);
      af[fi][2] = f2bf(t0.z); af[fi][3] = f2bf(t0.w);
      af[fi][4] = f2bf(t1.x); af[fi][5] = f2bf(t1.y);
      af[fi][6] = f2bf(t1.z); af[fi][7] = f2bf(t1.w);
    }
#pragma unroll
    for (int fj = 0; fj < 4; ++fj) {
      int row = nb + wn * 64 + fj * 16 + lr;
      const float4* up = (const float4*)(U + (size_t)row * RANK + kk * 32 + lg * 8);
      float4 u0 = up[0], u1 = up[1];
      bfr[fj][0] = f2bf(u0.x); bfr[fj][1] = f2bf(u0.y);
      bfr[fj][2] = f2bf(u0.z); bfr[fj][3] = f2bf(u0.w);
      bfr[fj][4] = f2bf(u1.x); bfr[fj][5] = f2bf(u1.y);
      bfr[fj][6] = f2bf(u1.z); bfr[fj][7] = f2bf(u1.w);
    }
#pragma unroll
    for (int fi = 0; fi < 4; ++fi)
#pragma unroll
      for (int fj = 0; fj < 4; ++fj)
        acc[fi][fj] = __builtin_amdgcn_mfma_f32_16x16x32_bf16(af[fi], bfr[fj], acc[fi][fj], 0, 0, 0);
  }
#pragma unroll
  for (int fj = 0; fj < 4; ++fj) {
    int o = nb + wn * 64 + fj * 16 + lr;
    float b = bias[o];
#pragma unroll
    for (int fi = 0; fi < 4; ++fi)
#pragma unroll
      for (int r = 0; r < 4; ++r) {
        int tok = mb + wm * 64 + fi * 16 + lg * 4 + r;
        out[(size_t)tok * OUT_F + o] = b + acc[fi][fj][r];
      }
  }
}

// K4: outliers — per-token LDS accumulator + one coalesced RMW pass
__global__ __launch_bounds__(256) void k_outlier(const unsigned short* __restrict__ Abf,
                                                 const int* __restrict__ rows,
                                                 const int* __restrict__ cols,
                                                 const float* __restrict__ vals,
                                                 const float* __restrict__ act,
                                                 float* __restrict__ out) {
  __shared__ float accr[OUT_F];
  int tk = blockIdx.x;
  for (int i = threadIdx.x; i < OUT_F; i += 256) accr[i] = 0.f;
  __syncthreads();
  float a = act[0];
  for (int i = threadIdx.x; i < NNZ; i += 256) {
    int r = rows[i], c = cols[i];
    float v = vals[i];
    float xq = bf2f(Abf[(size_t)tk * IN_F + c]);
    atomicAdd(accr + r, a * xq * v);
  }
  __syncthreads();
  float* orow = out + (size_t)tk * OUT_F;
  for (int i = threadIdx.x; i < OUT_F; i += 256) orow[i] += accr[i];
}

// K5: out += x_q @ Wq^T * (a*wscale[o]); i8 MFMA, BM=512 (W read once),
// BN=64, BK=64, KSPLIT=4, 8 waves, dbuf LDS, 2 blocks/CU.
__global__ __launch_bounds__(512, 4) void k_gemm(const unsigned char* __restrict__ Aq,
                                                 const int* __restrict__ W,
                                                 const float* __restrict__ wscale,
                                                 const float* __restrict__ act,
                                                 float* __restrict__ out) {
  __shared__ __align__(16) unsigned char As[2][512 * BK];
  __shared__ __align__(16) unsigned char Bs[2][BN * BK];

  // bijective decode: 2 XCDs per ks so each A k-slice (1MB) is L2-resident
  int d = blockIdx.x;
  int xcd = d & 7, idx = d >> 3;
  int ks = xcd >> 1;
  int nb = idx * 2 + (xcd & 1);   // 0..127
  int kb0 = ks * KRANGE;

  int tid = threadIdx.x, w = tid >> 6, l = tid & 63;
  int lr = l & 15, lg = l >> 4;
  int wm = w >> 1, wn = w & 1;    // 4M x 2N waves; wave tile 128x32

  int4v acc[8][2] = {};
  int4v wreg[2];

  const int rB = tid >> 3;          // W row 0..63
  const int kcB = (tid & 7) * 8;    // int32 (=byte) offset within BK

  auto LOAD_W = [&](int kb) {
    const int* wp = W + (size_t)(nb * BN + rB) * IN_F + kb + kcB;
    wreg[0] = *(const int4v*)wp;
    wreg[1] = *(const int4v*)(wp + 4);
  };
  // A i8 -> LDS direct; linear dest, pre-swizzled source (u ^= row&3)
  auto STAGE_A = [&](unsigned char* Abuf, int kb) {
#pragma unroll
    for (int i = 0; i < 4; ++i) {
      int ubase = i * 512 + w * 64;
      int ell = ubase + l;
      int r = ell >> 2, up = ell & 3;
      int u = up ^ (r & 3);
      gload_lds16(Aq + (size_t)r * IN_F + kb + u * 16, Abuf + (size_t)ubase * 16);
    }
  };
  // pack 8 int32 -> 8 i8, write swizzled
  auto WRITE_B = [&](unsigned char* Bbuf) {
    unsigned int w0 = 0, w1 = 0;
#pragma unroll
    for (int j = 0; j < 4; ++j) w0 |= ((unsigned)(wreg[0][j] & 0xFF)) << (8 * j);
#pragma unroll
    for (int j = 0; j < 4; ++j) w1 |= ((unsigned)(wreg[1][j] & 0xFF)) << (8 * j);
    int u = kcB >> 4, sub = (kcB >> 3) & 1;
    int us = u ^ (rB & 3);
    uint2 val; val.x = w0; val.y = w1;
    *(uint2*)(Bbuf + (size_t)rB * BK + us * 16 + sub * 8) = val;
  };
  auto LDF = [&](const unsigned char* buf, int row) -> int4v {
    int u = lg ^ (row & 3);
    return *(const int4v*)(buf + (size_t)row * BK + u * 16);
  };

  LOAD_W(kb0);
  STAGE_A(As[0], kb0);
  WRITE_B(Bs[0]);
  __syncthreads();

  for (int kt = 0; kt < NT; ++kt) {
    const int cur = kt & 1;
    const unsigned char* Ac = As[cur];
    const unsigned char* Bc = Bs[cur];
    if (kt + 1 < NT) {
      LOAD_W(kb0 + (kt + 1) * BK);
      STAGE_A(As[cur ^ 1], kb0 + (kt + 1) * BK);
    }
    int4v b0 = LDF(Bc, wn * 32 + lr);
    int4v b1 = LDF(Bc, wn * 32 + 16 + lr);
#pragma unroll
    for (int fi = 0; fi < 8; ++fi) {
      int4v af = LDF(Ac, wm * 128 + fi * 16 + lr);
      acc[fi][0] = __builtin_amdgcn_mfma_i32_16x16x64_i8(af, b0, acc[fi][0], 0, 0, 0);
      acc[fi][1] = __builtin_amdgcn_mfma_i32_16x16x64_i8(af, b1, acc[fi][1], 0, 0, 0);
    }
    if (kt + 1 < NT) WRITE_B(Bs[cur ^ 1]);
    __syncthreads();
  }

  float a = act[0];
#pragma unroll
  for (int fj = 0; fj < 2; ++fj) {
    int o = nb * BN + wn * 32 + fj * 16 + lr;
    float sc = a * wscale[o];
#pragma unroll
    for (int fi = 0; fi < 8; ++fi)
#pragma unroll
      for (int rr = 0; rr < 4; ++rr) {
        int tok = wm * 128 + fi * 16 + lg * 4 + rr;
        atomicAdd(out + (size_t)tok * OUT_F + o, (float)acc[fi][fj][rr] * sc);
      }
  }
}

extern "C" void kernel_launch(void* const* d_in, const int* in_sizes, int n_in,
                              void* d_out, int out_size, void* d_ws, size_t ws_size,
                              hipStream_t stream) {
  const float* x = (const float*)d_in[0];
  const int* W = (const int*)d_in[1];
  const float* wscale = (const float*)d_in[2];
  const float* smooth = (const float*)d_in[3];
  const float* act = (const float*)d_in[4];
  const int* orow = (const int*)d_in[5];
  const int* ocol = (const int*)d_in[6];
  const float* oval = (const float*)d_in[7];
  const float* U = (const float*)d_in[8];
  const float* S = (const float*)d_in[9];
  const float* V = (const float*)d_in[10];
  const float* bias = (const float*)d_in[11];
  float* out = (float*)d_out;

  unsigned short* Abf = (unsigned short*)d_ws;                       // 8 MB
  unsigned char* Aq = (unsigned char*)d_ws + (size_t)TOKENS * IN_F * 2;  // 4 MB
  float* t = (float*)((char*)d_ws + (size_t)TOKENS * IN_F * 3);      // 128 KB

  hipMemsetAsync(t, 0, TOKENS * RANK * sizeof(float), stream);
  k_quant<<<(TOKENS * IN_F / 4) / 256, 256, 0, stream>>>(x, smooth, act, Abf, Aq);
  k_lr1<<<64, 256, 0, stream>>>(Abf, V, S, act, t);
  k_lr2<<<256, 256, 0, stream>>>(t, U, bias, out);
  k_outlier<<<TOKENS, 256, 0, stream>>>(Abf, orow, ocol, oval, act, out);
  k_gemm<<<512, 512, 0, stream>>>(Aq, W, wscale, act, out);
}